// Round 2
// baseline (440.497 us; speedup 1.0000x reference)
//
#include <hip/hip_runtime.h>

#define B_  16
#define S_  1024
#define D_  384
#define QK_ 64

typedef __attribute__((ext_vector_type(8))) short bf16x8;
typedef __attribute__((ext_vector_type(4))) short bf16x4;
typedef __attribute__((ext_vector_type(4))) float f32x4;

__device__ __forceinline__ short f2bf(float f) {
  union { float f; unsigned u; } v; v.f = f;
  unsigned r = v.u + 0x7FFFu + ((v.u >> 16) & 1u);   // round-to-nearest-even
  return (short)(r >> 16);
}

__device__ __forceinline__ bf16x8 cvt8(const float4 a, const float4 b) {
  bf16x8 r;
  r[0] = f2bf(a.x); r[1] = f2bf(a.y); r[2] = f2bf(a.z); r[3] = f2bf(a.w);
  r[4] = f2bf(b.x); r[5] = f2bf(b.y); r[6] = f2bf(b.z); r[7] = f2bf(b.w);
  return r;
}

// ---------------------------------------------------------------------------
// K0: Xt[b][c][j] = bf16(x[b][j][c]).  64x64 tiles through LDS.
// 25 MB read + 12.6 MB write; runs once (~8 us). Conflicts in the scalar LDS
// transpose writes are acceptable here — this is the ONLY transpose in the
// pipeline (was previously inside k_out's K-loop = 84 us of conflict cycles).
// ---------------------------------------------------------------------------
__global__ __launch_bounds__(256) void k_prep(
    const float* __restrict__ x, unsigned short* __restrict__ Xt) {
  __shared__ __attribute__((aligned(16))) short t[64 * 72];   // [c][j]
  const int gid = blockIdx.x;
  const int b = gid / 96, r96 = gid % 96;
  const int jt = r96 / 6, ct = r96 % 6;
  const int j0 = jt * 64, c0 = ct * 64;
  const int tid = threadIdx.x;
#pragma unroll
  for (int r = 0; r < 4; ++r) {
    int li = tid + 256 * r;            // 0..1023
    int jj = li >> 4, f4 = li & 15;    // 64 j-rows x 16 float4
    float4 v = *(const float4*)&x[(size_t)(b * S_ + j0 + jj) * D_ + c0 + f4 * 4];
    t[(f4 * 4 + 0) * 72 + jj] = f2bf(v.x);
    t[(f4 * 4 + 1) * 72 + jj] = f2bf(v.y);
    t[(f4 * 4 + 2) * 72 + jj] = f2bf(v.z);
    t[(f4 * 4 + 3) * 72 + jj] = f2bf(v.w);
  }
  __syncthreads();
#pragma unroll
  for (int r = 0; r < 2; ++r) {
    int li = tid + 256 * r;            // 0..511
    int cc = li >> 3, q8 = li & 7;     // 64 c-rows x 8 uint4
    *(uint4*)&Xt[(size_t)(b * D_ + c0 + cc) * S_ + j0 + q8 * 8] =
        *(const uint4*)&t[cc * 72 + q8 * 8];
  }
}

// ---------------------------------------------------------------------------
// K1: projections. One block per position. x[:,pos,:] staged once in LDS
// (A-frags); WEIGHTS go global->reg directly: the B-fragment for 16x16x32 is
// W[row = tile*16+col][k = ks*32+quad*8 ..+7] — 32B contiguous fp32 per lane,
// perfectly coalesced (4 quads cover 128B per row). No weight LDS, 1 barrier.
// Waves 0,1 -> Q (scaled,+bias); waves 2,3 -> K. bf16 out to workspace.
// ---------------------------------------------------------------------------
__global__ __launch_bounds__(256) void k_proj(
    const float* __restrict__ x, const float* __restrict__ qw,
    const float* __restrict__ qb, const float* __restrict__ kw,
    unsigned short* __restrict__ Qb, unsigned short* __restrict__ Kb) {
  __shared__ __attribute__((aligned(16))) short xs[16 * 392];
  const int pos  = blockIdx.x;
  const int tid  = threadIdx.x;
  const int lane = tid & 63;
  const int w    = tid >> 6;
  const int col  = lane & 15;
  const int quad = lane >> 4;

#pragma unroll
  for (int r = 0; r < 6; ++r) {
    int li = tid + 256 * r;
    int brow = li / 96, c4 = li % 96;
    float4 v = *(const float4*)&x[(size_t)(brow * S_ + pos) * D_ + 4 * c4];
    bf16x4 c; c[0]=f2bf(v.x); c[1]=f2bf(v.y); c[2]=f2bf(v.z); c[3]=f2bf(v.w);
    *(bf16x4*)&xs[brow * 392 + 4 * c4] = c;
  }
  __syncthreads();

  const bool isQ = (w < 2);
  const int jt0 = (w & 1) * 2;                       // tiles {0,1} or {2,3}
  const float* wp = isQ ? qw : kw;
  const float* p0 = wp + (size_t)(pos * 64 + jt0 * 16 + col) * D_ + quad * 8;
  const float* p1 = p0 + 16 * D_;

  f32x4 acc0 = {0.f,0.f,0.f,0.f};
  f32x4 acc1 = {0.f,0.f,0.f,0.f};
#pragma unroll 4
  for (int ks = 0; ks < 12; ++ks) {
    float4 a0 = *(const float4*)(p0 + ks * 32);
    float4 a1 = *(const float4*)(p0 + ks * 32 + 4);
    float4 b0 = *(const float4*)(p1 + ks * 32);
    float4 b1 = *(const float4*)(p1 + ks * 32 + 4);
    bf16x8 aF = *(const bf16x8*)&xs[col * 392 + ks * 32 + quad * 8];
    acc0 = __builtin_amdgcn_mfma_f32_16x16x32_bf16(aF, cvt8(a0, a1), acc0, 0, 0, 0);
    acc1 = __builtin_amdgcn_mfma_f32_16x16x32_bf16(aF, cvt8(b0, b1), acc1, 0, 0, 0);
  }

  const float SCALE = 0.051031036307982884f;   // 384^-0.5
#pragma unroll
  for (int a = 0; a < 2; ++a) {
    const f32x4 acc = a ? acc1 : acc0;
    const int j = (jt0 + a) * 16 + col;              // C/D: col = n
#pragma unroll
    for (int r = 0; r < 4; ++r) {
      const int brow = quad * 4 + r;                 // C/D: row = m = batch
      float v = acc[r];
      if (isQ) {
        v = SCALE * (v + qb[pos * 64 + j]);
        Qb[(size_t)(brow * S_ + pos) * QK_ + j] = (unsigned short)f2bf(v);
      } else {
        Kb[(size_t)(brow * S_ + pos) * QK_ + j] = (unsigned short)f2bf(v);
      }
    }
  }
}

// ---------------------------------------------------------------------------
// K2: fused logits + bias + row softmax. Block = (b, 16 i-rows); each wave
// owns j in [w*256, w*256+256) = 16 j-tiles, full row in registers (16 f32x4).
// Q/K fragments loaded straight from global (contiguous 16B). Row reductions:
// shuffle across the 16 cols, then tiny LDS combine across waves.
// Writes attn fp32 (output) and P bf16 (for k_out).
// ---------------------------------------------------------------------------
__global__ __launch_bounds__(256) void k_attn(
    const unsigned short* __restrict__ Qb, const unsigned short* __restrict__ Kb,
    const float* __restrict__ bias, float* __restrict__ attn,
    unsigned short* __restrict__ Pb) {
  __shared__ float rm[4][16];
  __shared__ float rs[4][16];
  const int b  = blockIdx.x >> 6;
  const int i0 = (blockIdx.x & 63) * 16;
  const int tid = threadIdx.x, lane = tid & 63, w = tid >> 6;
  const int col = lane & 15, quad = lane >> 4;

  const unsigned short* qrow = Qb + (size_t)(b * S_ + i0 + col) * QK_;
  const bf16x8 aF0 = *(const bf16x8*)(qrow);
  const bf16x8 aF1 = *(const bf16x8*)(qrow + 32);
  // lane holds a0 at k=quad*8; full A-frag k = quad*8..+7 per the layout
  const bf16x8 aQ0 = *(const bf16x8*)(qrow + quad * 8);
  const bf16x8 aQ1 = *(const bf16x8*)(qrow + 32 + quad * 8);
  (void)aF0; (void)aF1;

  f32x4 acc[16];
#pragma unroll
  for (int s = 0; s < 16; ++s) acc[s] = (f32x4){0.f,0.f,0.f,0.f};

  const unsigned short* kbase = Kb + (size_t)b * S_ * QK_ + (size_t)(w * 256 + col) * QK_;
#pragma unroll 4
  for (int s = 0; s < 16; ++s) {
    const unsigned short* krow = kbase + (size_t)s * 16 * QK_;
    bf16x8 b0 = *(const bf16x8*)(krow + quad * 8);
    bf16x8 b1 = *(const bf16x8*)(krow + 32 + quad * 8);
    acc[s] = __builtin_amdgcn_mfma_f32_16x16x32_bf16(aQ0, b0, acc[s], 0, 0, 0);
    acc[s] = __builtin_amdgcn_mfma_f32_16x16x32_bf16(aQ1, b1, acc[s], 0, 0, 0);
  }

  // + bias, per-row max
  float pm[4] = {-1e30f, -1e30f, -1e30f, -1e30f};
#pragma unroll 4
  for (int s = 0; s < 16; ++s) {
    const int j = w * 256 + s * 16 + col;
#pragma unroll
    for (int r = 0; r < 4; ++r) {
      acc[s][r] += bias[(size_t)(i0 + quad * 4 + r) * S_ + j];
      pm[r] = fmaxf(pm[r], acc[s][r]);
    }
  }
#pragma unroll
  for (int m = 1; m < 16; m <<= 1) {
#pragma unroll
    for (int r = 0; r < 4; ++r) pm[r] = fmaxf(pm[r], __shfl_xor(pm[r], m));
  }
  if (col == 0) {
#pragma unroll
    for (int r = 0; r < 4; ++r) rm[w][quad * 4 + r] = pm[r];
  }
  __syncthreads();
#pragma unroll
  for (int r = 0; r < 4; ++r) {
    const int i = quad * 4 + r;
    pm[r] = fmaxf(fmaxf(rm[0][i], rm[1][i]), fmaxf(rm[2][i], rm[3][i]));
  }

  // exp + per-row sum
  float ps[4] = {0.f, 0.f, 0.f, 0.f};
#pragma unroll 4
  for (int s = 0; s < 16; ++s) {
#pragma unroll
    for (int r = 0; r < 4; ++r) {
      float e = __expf(acc[s][r] - pm[r]);
      acc[s][r] = e;
      ps[r] += e;
    }
  }
#pragma unroll
  for (int m = 1; m < 16; m <<= 1) {
#pragma unroll
    for (int r = 0; r < 4; ++r) ps[r] += __shfl_xor(ps[r], m);
  }
  if (col == 0) {
#pragma unroll
    for (int r = 0; r < 4; ++r) rs[w][quad * 4 + r] = ps[r];
  }
  __syncthreads();
#pragma unroll
  for (int r = 0; r < 4; ++r) {
    const int i = quad * 4 + r;
    ps[r] = 1.0f / (rs[0][i] + rs[1][i] + rs[2][i] + rs[3][i]);
  }

  // write attn fp32 + P bf16
#pragma unroll 4
  for (int s = 0; s < 16; ++s) {
    const int j = w * 256 + s * 16 + col;
#pragma unroll
    for (int r = 0; r < 4; ++r) {
      const size_t row = (size_t)(b * S_ + i0 + quad * 4 + r);
      float v = acc[s][r] * ps[r];
      attn[row * S_ + j] = v;
      Pb[row * S_ + j] = (unsigned short)f2bf(v);
    }
  }
}

// ---------------------------------------------------------------------------
// K3: out = P @ X.  Block = 64i x 192c, K-step 64 over j. Both operands bf16,
// pre-laid-out (Pb row-major in j; Xt row-major in j) -> all LDS staging is
// contiguous uint4 writes (2-way aliasing max = free), reads ds_read_b128.
// ---------------------------------------------------------------------------
__global__ __launch_bounds__(256) void k_out(
    const unsigned short* __restrict__ Pb, const unsigned short* __restrict__ Xt,
    float* __restrict__ out) {
  __shared__ __attribute__((aligned(16))) short Ps[64 * 72];    // [i][j]
  __shared__ __attribute__((aligned(16))) short Xs[192 * 72];   // [c][j]
  const int gid = blockIdx.x;
  const int b = gid >> 5, r32 = gid & 31;
  const int it = r32 >> 1, ch = r32 & 1;
  const int i0 = it * 64, c0 = ch * 192;
  const int tid = threadIdx.x, lane = tid & 63, w = tid >> 6;
  const int col = lane & 15, quad = lane >> 4;

  f32x4 acc[12];
#pragma unroll
  for (int s = 0; s < 12; ++s) acc[s] = (f32x4){0.f,0.f,0.f,0.f};

  for (int j0 = 0; j0 < S_; j0 += 64) {
    __syncthreads();
#pragma unroll
    for (int r = 0; r < 2; ++r) {
      int li = tid + 256 * r;            // 512: 64 i-rows x 8 uint4
      int ii = li >> 3, q8 = li & 7;
      *(uint4*)&Ps[ii * 72 + q8 * 8] =
          *(const uint4*)&Pb[(size_t)(b * S_ + i0 + ii) * S_ + j0 + q8 * 8];
    }
#pragma unroll
    for (int r = 0; r < 6; ++r) {
      int li = tid + 256 * r;            // 1536: 192 c-rows x 8 uint4
      int cc = li >> 3, q8 = li & 7;
      *(uint4*)&Xs[cc * 72 + q8 * 8] =
          *(const uint4*)&Xt[(size_t)(b * D_ + c0 + cc) * S_ + j0 + q8 * 8];
    }
    __syncthreads();
#pragma unroll
    for (int ks = 0; ks < 2; ++ks) {
      bf16x8 aF = *(const bf16x8*)&Ps[(w * 16 + col) * 72 + ks * 32 + quad * 8];
#pragma unroll
      for (int s = 0; s < 12; ++s) {
        bf16x8 bF = *(const bf16x8*)&Xs[(s * 16 + col) * 72 + ks * 32 + quad * 8];
        acc[s] = __builtin_amdgcn_mfma_f32_16x16x32_bf16(aF, bF, acc[s], 0, 0, 0);
      }
    }
  }
#pragma unroll
  for (int s = 0; s < 12; ++s) {
    const int c = c0 + s * 16 + col;
#pragma unroll
    for (int r = 0; r < 4; ++r) {
      const int i = i0 + w * 16 + quad * 4 + r;
      out[(size_t)(b * S_ + i) * D_ + c] = acc[s][r];
    }
  }
}

extern "C" void kernel_launch(void* const* d_in, const int* in_sizes, int n_in,
                              void* d_out, int out_size, void* d_ws, size_t ws_size,
                              hipStream_t stream) {
  const float* x  = (const float*)d_in[0];
  const float* qw = (const float*)d_in[1];
  const float* qb = (const float*)d_in[2];
  const float* kw = (const float*)d_in[3];
  const float* ab = (const float*)d_in[4];

  float* out  = (float*)d_out;
  float* attn = out + (size_t)B_ * S_ * D_;            // outputs concatenated

  unsigned short* Qb = (unsigned short*)d_ws;          // bf16 [B][S][64]   2 MB
  unsigned short* Kb = Qb + (size_t)B_ * S_ * QK_;     // bf16 [B][S][64]   2 MB
  unsigned short* Xt = Kb + (size_t)B_ * S_ * QK_;     // bf16 [B][D][S]  12.6 MB
  unsigned short* Pb = Xt + (size_t)B_ * D_ * S_;      // bf16 [B][S][S]  33.5 MB

  k_prep<<<B_ * 16 * 6, 256, 0, stream>>>(x, Xt);
  k_proj<<<S_,          256, 0, stream>>>(x, qw, qb, kw, Qb, Kb);
  k_attn<<<B_ * 64,     256, 0, stream>>>(Qb, Kb, ab, attn, Pb);
  k_out <<<B_ * 16 * 2, 256, 0, stream>>>(Pb, Xt, out);
}

// Round 3
// 438.251 us; speedup vs baseline: 1.0051x; 1.0051x over previous
//
#include <hip/hip_runtime.h>

#define B_  16
#define S_  1024
#define D_  384
#define QK_ 64

typedef __attribute__((ext_vector_type(8))) short bf16x8;
typedef __attribute__((ext_vector_type(4))) short bf16x4;
typedef __attribute__((ext_vector_type(4))) float f32x4;

__device__ __forceinline__ short f2bf(float f) {
  union { float f; unsigned u; } v; v.f = f;
  unsigned r = v.u + 0x7FFFu + ((v.u >> 16) & 1u);   // round-to-nearest-even
  return (short)(r >> 16);
}

__device__ __forceinline__ bf16x8 cvt8(const float4 a, const float4 b) {
  bf16x8 r;
  r[0] = f2bf(a.x); r[1] = f2bf(a.y); r[2] = f2bf(a.z); r[3] = f2bf(a.w);
  r[4] = f2bf(b.x); r[5] = f2bf(b.y); r[6] = f2bf(b.z); r[7] = f2bf(b.w);
  return r;
}

// ---------------------------------------------------------------------------
// K0: Xt[b][c][j] = bf16(x[b][j][c]).  64x64 tiles through LDS. Stores are
// uint4 with 8 lanes/row = 128 B full lines. Runs once (~8 us).
// ---------------------------------------------------------------------------
__global__ __launch_bounds__(256) void k_prep(
    const float* __restrict__ x, unsigned short* __restrict__ Xt) {
  __shared__ __attribute__((aligned(16))) short t[64 * 72];   // [c][j]
  const int gid = blockIdx.x;
  const int b = gid / 96, r96 = gid % 96;
  const int jt = r96 / 6, ct = r96 % 6;
  const int j0 = jt * 64, c0 = ct * 64;
  const int tid = threadIdx.x;
#pragma unroll
  for (int r = 0; r < 4; ++r) {
    int li = tid + 256 * r;            // 0..1023
    int jj = li >> 4, f4 = li & 15;    // 64 j-rows x 16 float4
    float4 v = *(const float4*)&x[(size_t)(b * S_ + j0 + jj) * D_ + c0 + f4 * 4];
    t[(f4 * 4 + 0) * 72 + jj] = f2bf(v.x);
    t[(f4 * 4 + 1) * 72 + jj] = f2bf(v.y);
    t[(f4 * 4 + 2) * 72 + jj] = f2bf(v.z);
    t[(f4 * 4 + 3) * 72 + jj] = f2bf(v.w);
  }
  __syncthreads();
#pragma unroll
  for (int r = 0; r < 2; ++r) {
    int li = tid + 256 * r;            // 0..511
    int cc = li >> 3, q8 = li & 7;     // 64 c-rows x 8 uint4
    *(uint4*)&Xt[(size_t)(b * D_ + c0 + cc) * S_ + j0 + q8 * 8] =
        *(const uint4*)&t[cc * 72 + q8 * 8];
  }
}

// ---------------------------------------------------------------------------
// K1: projections. One block per position; x[:,pos,:] staged in LDS (A-frag),
// weights global->reg (a wave's 64 lanes fully cover 16 rows x 128 B lines).
// Epilogue: Q/K results staged in LDS, then flat uint4 copy -> every Qb/Kb
// row chunk is exactly one full 128 B line (was 32 B partial-line scalars).
// ---------------------------------------------------------------------------
__global__ __launch_bounds__(256) void k_proj(
    const float* __restrict__ x, const float* __restrict__ qw,
    const float* __restrict__ qb, const float* __restrict__ kw,
    unsigned short* __restrict__ Qb, unsigned short* __restrict__ Kb) {
  __shared__ __attribute__((aligned(16))) short xs[16 * 392];
  __shared__ __attribute__((aligned(16))) short qk[2 * 16 * 72];
  const int pos  = blockIdx.x;
  const int tid  = threadIdx.x;
  const int lane = tid & 63;
  const int w    = tid >> 6;
  const int col  = lane & 15;
  const int quad = lane >> 4;

#pragma unroll
  for (int r = 0; r < 6; ++r) {
    int li = tid + 256 * r;
    int brow = li / 96, c4 = li % 96;
    float4 v = *(const float4*)&x[(size_t)(brow * S_ + pos) * D_ + 4 * c4];
    bf16x4 c; c[0]=f2bf(v.x); c[1]=f2bf(v.y); c[2]=f2bf(v.z); c[3]=f2bf(v.w);
    *(bf16x4*)&xs[brow * 392 + 4 * c4] = c;
  }
  __syncthreads();

  const bool isQ = (w < 2);
  const int jt0 = (w & 1) * 2;                       // tiles {0,1} or {2,3}
  const float* wp = isQ ? qw : kw;
  const float* p0 = wp + (size_t)(pos * 64 + jt0 * 16 + col) * D_ + quad * 8;
  const float* p1 = p0 + 16 * D_;

  f32x4 acc0 = {0.f,0.f,0.f,0.f};
  f32x4 acc1 = {0.f,0.f,0.f,0.f};
#pragma unroll 4
  for (int ks = 0; ks < 12; ++ks) {
    float4 a0 = *(const float4*)(p0 + ks * 32);
    float4 a1 = *(const float4*)(p0 + ks * 32 + 4);
    float4 b0 = *(const float4*)(p1 + ks * 32);
    float4 b1 = *(const float4*)(p1 + ks * 32 + 4);
    bf16x8 aF = *(const bf16x8*)&xs[col * 392 + ks * 32 + quad * 8];
    acc0 = __builtin_amdgcn_mfma_f32_16x16x32_bf16(aF, cvt8(a0, a1), acc0, 0, 0, 0);
    acc1 = __builtin_amdgcn_mfma_f32_16x16x32_bf16(aF, cvt8(b0, b1), acc1, 0, 0, 0);
  }

  const float SCALE = 0.051031036307982884f;   // 384^-0.5
  const int qko = isQ ? 0 : (16 * 72);
#pragma unroll
  for (int a = 0; a < 2; ++a) {
    const f32x4 acc = a ? acc1 : acc0;
    const int j = (jt0 + a) * 16 + col;              // C/D: col = n
#pragma unroll
    for (int r = 0; r < 4; ++r) {
      float v = acc[r];
      if (isQ) v = SCALE * (v + qb[pos * 64 + j]);
      qk[qko + (quad * 4 + r) * 72 + j] = f2bf(v);   // row = batch index
    }
  }
  __syncthreads();
  {
    const int half = tid >> 7;           // 0 = Q, 1 = K
    const int row  = (tid >> 3) & 15;    // batch index
    const int seg  = tid & 7;
    uint4 v = *(const uint4*)&qk[half * (16 * 72) + row * 72 + seg * 8];
    unsigned short* dst = half ? Kb : Qb;
    *(uint4*)&dst[(size_t)(row * S_ + pos) * QK_ + seg * 8] = v;   // full line
  }
}

// ---------------------------------------------------------------------------
// K2: fused logits + bias + row softmax. Block = (b, 16 i-rows); wave w owns
// j in [w*256, w*256+256). Epilogue: per-wave LDS transpose in 64-j chunks
// (row stride 68 fp32 -> 2-way aliasing = free; same-wave LDS, no barrier),
// then attn stored as 16-lane float4 rows (256 B contiguous) and Pb as
// 16-lane bf16x4 rows (128 B) -> no partial-line RMW at L2/HBM.
// ---------------------------------------------------------------------------
__global__ __launch_bounds__(256) void k_attn(
    const unsigned short* __restrict__ Qb, const unsigned short* __restrict__ Kb,
    const float* __restrict__ bias, float* __restrict__ attn,
    unsigned short* __restrict__ Pb) {
  __shared__ float rm[4][16];
  __shared__ float rs[4][16];
  __shared__ __attribute__((aligned(16))) float tz[4][16 * 68];
  const int b  = blockIdx.x >> 6;
  const int i0 = (blockIdx.x & 63) * 16;
  const int tid = threadIdx.x, lane = tid & 63, w = tid >> 6;
  const int col = lane & 15, quad = lane >> 4;

  const unsigned short* qrow = Qb + (size_t)(b * S_ + i0 + col) * QK_;
  const bf16x8 aQ0 = *(const bf16x8*)(qrow + quad * 8);
  const bf16x8 aQ1 = *(const bf16x8*)(qrow + 32 + quad * 8);

  f32x4 acc[16];
#pragma unroll
  for (int s = 0; s < 16; ++s) acc[s] = (f32x4){0.f,0.f,0.f,0.f};

  const unsigned short* kbase = Kb + (size_t)b * S_ * QK_ + (size_t)(w * 256 + col) * QK_;
#pragma unroll 4
  for (int s = 0; s < 16; ++s) {
    const unsigned short* krow = kbase + (size_t)s * 16 * QK_;
    bf16x8 b0 = *(const bf16x8*)(krow + quad * 8);
    bf16x8 b1 = *(const bf16x8*)(krow + 32 + quad * 8);
    acc[s] = __builtin_amdgcn_mfma_f32_16x16x32_bf16(aQ0, b0, acc[s], 0, 0, 0);
    acc[s] = __builtin_amdgcn_mfma_f32_16x16x32_bf16(aQ1, b1, acc[s], 0, 0, 0);
  }

  // + bias, per-row max
  float pm[4] = {-1e30f, -1e30f, -1e30f, -1e30f};
#pragma unroll 4
  for (int s = 0; s < 16; ++s) {
    const int j = w * 256 + s * 16 + col;
#pragma unroll
    for (int r = 0; r < 4; ++r) {
      acc[s][r] += bias[(size_t)(i0 + quad * 4 + r) * S_ + j];
      pm[r] = fmaxf(pm[r], acc[s][r]);
    }
  }
#pragma unroll
  for (int m = 1; m < 16; m <<= 1) {
#pragma unroll
    for (int r = 0; r < 4; ++r) pm[r] = fmaxf(pm[r], __shfl_xor(pm[r], m));
  }
  if (col == 0) {
#pragma unroll
    for (int r = 0; r < 4; ++r) rm[w][quad * 4 + r] = pm[r];
  }
  __syncthreads();
#pragma unroll
  for (int r = 0; r < 4; ++r) {
    const int i = quad * 4 + r;
    pm[r] = fmaxf(fmaxf(rm[0][i], rm[1][i]), fmaxf(rm[2][i], rm[3][i]));
  }

  // exp + per-row sum
  float ps[4] = {0.f, 0.f, 0.f, 0.f};
#pragma unroll 4
  for (int s = 0; s < 16; ++s) {
#pragma unroll
    for (int r = 0; r < 4; ++r) {
      float e = __expf(acc[s][r] - pm[r]);
      acc[s][r] = e;
      ps[r] += e;
    }
  }
#pragma unroll
  for (int m = 1; m < 16; m <<= 1) {
#pragma unroll
    for (int r = 0; r < 4; ++r) ps[r] += __shfl_xor(ps[r], m);
  }
  if (col == 0) {
#pragma unroll
    for (int r = 0; r < 4; ++r) rs[w][quad * 4 + r] = ps[r];
  }
  __syncthreads();
#pragma unroll
  for (int r = 0; r < 4; ++r) {
    const int i = quad * 4 + r;
    ps[r] = 1.0f / (rs[0][i] + rs[1][i] + rs[2][i] + rs[3][i]);
  }

  // epilogue: per-wave transpose in 64-j chunks, full-line stores
  float* tw = tz[w];
  for (int c = 0; c < 4; ++c) {
#pragma unroll
    for (int sl = 0; sl < 4; ++sl) {
#pragma unroll
      for (int r = 0; r < 4; ++r)
        tw[(quad * 4 + r) * 68 + sl * 16 + col] = acc[c * 4 + sl][r] * ps[r];
    }
#pragma unroll
    for (int it = 0; it < 4; ++it) {
      const int rr = it * 4 + quad;
      f32x4 v = *(const f32x4*)&tw[rr * 68 + col * 4];
      const size_t row = (size_t)(b * S_ + i0 + rr);
      const int j = w * 256 + c * 64 + col * 4;
      float4 fv; fv.x = v[0]; fv.y = v[1]; fv.z = v[2]; fv.w = v[3];
      *(float4*)&attn[row * S_ + j] = fv;
      bf16x4 pv; pv[0]=f2bf(v[0]); pv[1]=f2bf(v[1]); pv[2]=f2bf(v[2]); pv[3]=f2bf(v[3]);
      *(bf16x4*)&Pb[row * S_ + j] = pv;
    }
  }
}

// ---------------------------------------------------------------------------
// K3: out = P @ X.  Block = 64i x 192c, K-step 64 over j; clean uint4 LDS
// staging. Epilogue: out tile staged fp32 in LDS (reusing staging smem),
// then flat float4 copy -> full-line stores (row span 768 B, 128 B-aligned).
// ---------------------------------------------------------------------------
__global__ __launch_bounds__(256) void k_out(
    const unsigned short* __restrict__ Pb, const unsigned short* __restrict__ Xt,
    float* __restrict__ out) {
  __shared__ __attribute__((aligned(16))) char smem[64 * 196 * 4];  // 50176 B
  short* Ps = (short*)smem;                    // [64][72]
  short* Xs = (short*)smem + 64 * 72;          // [192][72]
  float* ot = (float*)smem;                    // [64][196]
  const int gid = blockIdx.x;
  const int b = gid >> 5, r32 = gid & 31;
  const int it = r32 >> 1, ch = r32 & 1;
  const int i0 = it * 64, c0 = ch * 192;
  const int tid = threadIdx.x, lane = tid & 63, w = tid >> 6;
  const int col = lane & 15, quad = lane >> 4;

  f32x4 acc[12];
#pragma unroll
  for (int s = 0; s < 12; ++s) acc[s] = (f32x4){0.f,0.f,0.f,0.f};

  for (int j0 = 0; j0 < S_; j0 += 64) {
    __syncthreads();
#pragma unroll
    for (int r = 0; r < 2; ++r) {
      int li = tid + 256 * r;            // 512: 64 i-rows x 8 uint4
      int ii = li >> 3, q8 = li & 7;
      *(uint4*)&Ps[ii * 72 + q8 * 8] =
          *(const uint4*)&Pb[(size_t)(b * S_ + i0 + ii) * S_ + j0 + q8 * 8];
    }
#pragma unroll
    for (int r = 0; r < 6; ++r) {
      int li = tid + 256 * r;            // 1536: 192 c-rows x 8 uint4
      int cc = li >> 3, q8 = li & 7;
      *(uint4*)&Xs[cc * 72 + q8 * 8] =
          *(const uint4*)&Xt[(size_t)(b * D_ + c0 + cc) * S_ + j0 + q8 * 8];
    }
    __syncthreads();
#pragma unroll
    for (int ks = 0; ks < 2; ++ks) {
      bf16x8 aF = *(const bf16x8*)&Ps[(w * 16 + col) * 72 + ks * 32 + quad * 8];
#pragma unroll
      for (int s = 0; s < 12; ++s) {
        bf16x8 bF = *(const bf16x8*)&Xs[(s * 16 + col) * 72 + ks * 32 + quad * 8];
        acc[s] = __builtin_amdgcn_mfma_f32_16x16x32_bf16(aF, bF, acc[s], 0, 0, 0);
      }
    }
  }

  __syncthreads();                       // staging reads done before overwrite
#pragma unroll
  for (int s = 0; s < 12; ++s) {
#pragma unroll
    for (int r = 0; r < 4; ++r)
      ot[(w * 16 + quad * 4 + r) * 196 + s * 16 + col] = acc[s][r];
  }
  __syncthreads();
#pragma unroll
  for (int itc = 0; itc < 12; ++itc) {
    int g = itc * 256 + tid;             // 3072 float4s = 64 rows x 48
    int row = g / 48, c4 = g % 48;
    f32x4 v = *(const f32x4*)&ot[row * 196 + c4 * 4];
    float4 fv; fv.x = v[0]; fv.y = v[1]; fv.z = v[2]; fv.w = v[3];
    *(float4*)&out[(size_t)(b * S_ + i0 + row) * D_ + c0 + c4 * 4] = fv;
  }
}

extern "C" void kernel_launch(void* const* d_in, const int* in_sizes, int n_in,
                              void* d_out, int out_size, void* d_ws, size_t ws_size,
                              hipStream_t stream) {
  const float* x  = (const float*)d_in[0];
  const float* qw = (const float*)d_in[1];
  const float* qb = (const float*)d_in[2];
  const float* kw = (const float*)d_in[3];
  const float* ab = (const float*)d_in[4];

  float* out  = (float*)d_out;
  float* attn = out + (size_t)B_ * S_ * D_;            // outputs concatenated

  unsigned short* Qb = (unsigned short*)d_ws;          // bf16 [B][S][64]   2 MB
  unsigned short* Kb = Qb + (size_t)B_ * S_ * QK_;     // bf16 [B][S][64]   2 MB
  unsigned short* Xt = Kb + (size_t)B_ * S_ * QK_;     // bf16 [B][D][S]  12.6 MB
  unsigned short* Pb = Xt + (size_t)B_ * D_ * S_;      // bf16 [B][S][S]  33.5 MB

  k_prep<<<B_ * 16 * 6, 256, 0, stream>>>(x, Xt);
  k_proj<<<S_,          256, 0, stream>>>(x, qw, qb, kw, Qb, Kb);
  k_attn<<<B_ * 64,     256, 0, stream>>>(Qb, Kb, ab, attn, Pb);
  k_out <<<B_ * 16 * 2, 256, 0, stream>>>(Pb, Xt, out);
}